// Round 1
// baseline (3745.358 us; speedup 1.0000x reference)
//
#include <hip/hip_runtime.h>
#include <math.h>

#define T_SEQ 2048
#define NHQ 32
#define NG 2
#define HD 64
#define CSTRIDE 16
#define SCALE 0.125f

// ---------------- GEMM: C[M,N] = A[M,K] * B[N,K]^T ----------------
__global__ __launch_bounds__(256) void gemm_abt(
    const float* __restrict__ A, const float* __restrict__ B,
    float* __restrict__ C, int M, int N, int K) {
  __shared__ __align__(16) float As[32][68];
  __shared__ __align__(16) float Bs[32][68];
  const int tx = threadIdx.x, ty = threadIdx.y;
  const int tid = ty * 16 + tx;
  const int m0 = blockIdx.y * 64, n0 = blockIdx.x * 64;
  float acc[4][4] = {};
  for (int k0 = 0; k0 < K; k0 += 32) {
    #pragma unroll
    for (int i = 0; i < 8; ++i) {
      int idx = tid + i * 256;
      int r = idx >> 5, kk = idx & 31;
      int gm = m0 + r, gn = n0 + r;
      As[kk][r] = (gm < M) ? A[(size_t)gm * K + k0 + kk] : 0.f;
      Bs[kk][r] = (gn < N) ? B[(size_t)gn * K + k0 + kk] : 0.f;
    }
    __syncthreads();
    #pragma unroll
    for (int kk = 0; kk < 32; ++kk) {
      float4 a4 = *reinterpret_cast<const float4*>(&As[kk][ty * 4]);
      float4 b4 = *reinterpret_cast<const float4*>(&Bs[kk][tx * 4]);
      float a_[4] = {a4.x, a4.y, a4.z, a4.w};
      float b_[4] = {b4.x, b4.y, b4.z, b4.w};
      #pragma unroll
      for (int i = 0; i < 4; ++i)
        #pragma unroll
        for (int j = 0; j < 4; ++j) acc[i][j] += a_[i] * b_[j];
    }
    __syncthreads();
  }
  #pragma unroll
  for (int i = 0; i < 4; ++i) {
    int gm = m0 + ty * 4 + i;
    if (gm >= M) continue;
    #pragma unroll
    for (int j = 0; j < 4; ++j) {
      int gn = n0 + tx * 4 + j;
      if (gn < N) C[(size_t)gm * N + gn] = acc[i][j];
    }
  }
}

// ---------------- RoPE (in-place on q and k) ----------------
__global__ __launch_bounds__(256) void rope_all(float* __restrict__ q,
                                                float* __restrict__ k) {
  const int t = blockIdx.x;
  const float lnb_over = 9.210340371976184f / 32.f;  // ln(10000)/32
  for (int job = threadIdx.x; job < (NHQ + NG) * 32; job += 256) {
    int h = job >> 5, j = job & 31;
    float* base = (h < NHQ) ? (q + ((size_t)t * NHQ + h) * HD)
                            : (k + ((size_t)t * NG + (h - NHQ)) * HD);
    float inv = expf(-(float)j * lnb_over);
    float fr = (float)t * inv;
    float c_ = cosf(fr), s_ = sinf(fr);
    float x1 = base[j], x2 = base[j + 32];
    base[j] = x1 * c_ - x2 * s_;
    base[j + 32] = x2 * c_ + x1 * s_;
  }
}

// ---------------- compression: ck/cv[c][g][d] ----------------
__global__ __launch_bounds__(256) void compress_kv(
    const float* __restrict__ k, const float* __restrict__ v,
    const float* __restrict__ Wck, const float* __restrict__ Wcv,
    float* __restrict__ ck, float* __restrict__ cv) {
  const int c = blockIdx.x, g = blockIdx.y;
  const int tid = threadIdx.x;
  const int d = tid & 63, chunk = tid >> 6;
  __shared__ float red[2][4][64];
  float ak = 0.f, av = 0.f;
  for (int f = chunk * 512; f < chunk * 512 + 512; ++f) {
    int i = f >> 6, e = f & 63;
    int trow = c * CSTRIDE + i;
    float kv = k[((size_t)trow * NG + g) * HD + e];
    float vv = v[((size_t)trow * NG + g) * HD + e];
    ak += kv * Wck[((size_t)g * 2048 + f) * HD + d];
    av += vv * Wcv[((size_t)g * 2048 + f) * HD + d];
  }
  red[0][chunk][d] = ak;
  red[1][chunk][d] = av;
  __syncthreads();
  if (tid < 64) {
    ck[((size_t)c * NG + g) * HD + tid] =
        red[0][0][tid] + red[0][1][tid] + red[0][2][tid] + red[0][3][tid];
  } else if (tid < 128) {
    int dd = tid - 64;
    cv[((size_t)c * NG + g) * HD + dd] =
        red[1][0][dd] + red[1][1][dd] + red[1][2][dd] + red[1][3][dd];
  }
}

// ------- compressed attention + block scores + top-16 selection -------
__global__ __launch_bounds__(128) void comp_attn(
    const float* __restrict__ q, const float* __restrict__ ck,
    const float* __restrict__ cv, const float* __restrict__ gr,
    float* __restrict__ comb, unsigned* __restrict__ sel) {
  const int t = blockIdx.x, g = blockIdx.y;
  const int tid = threadIdx.x;
  __shared__ float qs[16][64];
  __shared__ float p[16][128];
  __shared__ float sc[32];
  for (int i = tid; i < 1024; i += 128)
    qs[i >> 6][i & 63] = q[((size_t)t * NHQ + g * 16 + (i >> 6)) * HD + (i & 63)];
  __syncthreads();
  const int cmaxv = (t >= 31) ? min(126, (t - 31) >> 4) : -1;
  const int nv = cmaxv + 1;
  for (int h = 0; h < 16; ++h) {
    for (int c = tid; c < nv; c += 128) {
      const float* ckp = ck + ((size_t)c * NG + g) * HD;
      float acc = 0.f;
      #pragma unroll
      for (int e = 0; e < 64; ++e) acc += qs[h][e] * ckp[e];
      p[h][c] = acc * SCALE;
    }
  }
  __syncthreads();
  if (tid < 16) {  // per-head softmax over valid c
    const int h = tid;
    float mx = -INFINITY;
    for (int c = 0; c < nv; ++c) mx = fmaxf(mx, p[h][c]);
    float s = 0.f;
    for (int c = 0; c < nv; ++c) { float e_ = expf(p[h][c] - mx); p[h][c] = e_; s += e_; }
    float is = (nv > 0) ? 1.f / s : 0.f;
    for (int c = 0; c < nv; ++c) p[h][c] *= is;
  }
  __syncthreads();
  const float g0 = 1.f / (1.f + expf(-gr[t * 3 + 0]));
  for (int job = tid; job < 1024; job += 128) {  // comp_out, gated into comb
    int h = job >> 6, d = job & 63;
    float acc = 0.f;
    for (int c = 0; c < nv; ++c) acc += p[h][c] * cv[((size_t)c * NG + g) * HD + d];
    comb[((size_t)t * NHQ + g * 16 + h) * HD + d] = g0 * acc;
  }
  if (tid < 32) {  // block scores with forced/causal overrides
    const int b = tid, qb = t >> 6;
    float s;
    if (b > qb) s = -INFINITY;
    else if (b == 0 || qb - b < 2) s = INFINITY;
    else {
      s = 0.f;
      int clo = (4 * b - 1 > 0) ? 4 * b - 1 : 0;
      int chi = min(cmaxv, 4 * b + 3);
      for (int c = clo; c <= chi; ++c) {
        float cs_ = 0.f;
        for (int h = 0; h < 16; ++h) cs_ += p[h][c];
        s += cs_;
      }
    }
    sc[b] = s;
  }
  __syncthreads();
  if (tid == 0) {  // top-16, ties -> lowest index (matches jax.lax.top_k)
    unsigned m_ = 0;
    #pragma unroll 1
    for (int it = 0; it < 16; ++it) {
      float best = -INFINITY; int bi = -1;
      for (int b = 0; b < 32; ++b)
        if (sc[b] > best) { best = sc[b]; bi = b; }
      if (bi < 0) break;  // only -inf left -> tk_valid false
      m_ |= 1u << bi;
      sc[bi] = -INFINITY;
    }
    sel[t * NG + g] = m_;
  }
}

// ------- block-sparse (MODE 0) / sliding-window (MODE 1) attention -------
template <int MODE>
__global__ __launch_bounds__(256) void sel_attn(
    const float* __restrict__ q, const float* __restrict__ k,
    const float* __restrict__ v, const float* __restrict__ gr,
    const unsigned* __restrict__ sel, float* __restrict__ comb) {
  const int t = blockIdx.x, g = blockIdx.y;
  const int tid = threadIdx.x;
  const int lane = tid & 63, w = tid >> 6;
  __shared__ float qs[16][64];
  __shared__ float kb[64][65];  // +1 pad: 2-way bank alias only (free)
  __shared__ float vb[64][65];
  for (int i = tid; i < 1024; i += 256)
    qs[i >> 6][i & 63] = q[((size_t)t * NHQ + g * 16 + (i >> 6)) * HD + (i & 63)];
  float m[4], l[4], acc[4];
  #pragma unroll
  for (int h = 0; h < 4; ++h) { m[h] = -INFINITY; l[h] = 0.f; acc[h] = 0.f; }
  unsigned mrem = 0; int b0 = 0, nb;
  if (MODE == 0) { mrem = sel[t * NG + g]; nb = __popc(mrem); }
  else { b0 = (t >= 512) ? ((t - 512) >> 6) : 0; nb = (t >> 6) - b0 + 1; }
  for (int ib = 0; ib < nb; ++ib) {
    int b;
    if (MODE == 0) { b = __ffs(mrem) - 1; mrem &= mrem - 1; } else { b = b0 + ib; }
    __syncthreads();
    for (int i = tid; i < 4096; i += 256) {  // stage K,V block
      int r = i >> 6, cc = i & 63;
      int s = b * 64 + r;
      kb[r][cc] = k[((size_t)s * NG + g) * HD + cc];
      vb[r][cc] = v[((size_t)s * NG + g) * HD + cc];
    }
    __syncthreads();
    const int sg = b * 64 + lane;
    const bool ok = (MODE == 0) ? (sg <= t) : (sg <= t && t - sg <= 512);
    #pragma unroll
    for (int h = 0; h < 4; ++h) {  // wave handles 4 heads
      const int hh = w * 4 + h;
      float s_ = 0.f;
      #pragma unroll
      for (int d = 0; d < 64; ++d) s_ += qs[hh][d] * kb[lane][d];
      s_ = ok ? s_ * SCALE : -1e30f;
      float mx = s_;
      #pragma unroll
      for (int off = 32; off; off >>= 1) mx = fmaxf(mx, __shfl_xor(mx, off));
      float mnew = fmaxf(m[h], mx);
      float p_ = __expf(s_ - mnew);        // masked -> exp(-1e30) == 0
      float alpha = __expf(m[h] - mnew);   // first iter: exp(-inf) == 0
      float ps = p_;
      #pragma unroll
      for (int off = 32; off; off >>= 1) ps += __shfl_xor(ps, off);
      l[h] = l[h] * alpha + ps;
      float pv = 0.f;
      #pragma unroll
      for (int j = 0; j < 64; ++j) pv += __shfl(p_, j) * vb[j][lane];
      acc[h] = acc[h] * alpha + pv;
      m[h] = mnew;
    }
  }
  const float gv = 1.f / (1.f + __expf(-gr[t * 3 + (MODE == 0 ? 1 : 2)]));
  #pragma unroll
  for (int h = 0; h < 4; ++h) {
    const int hh = w * 4 + h;
    size_t idx = ((size_t)t * NHQ + g * 16 + hh) * HD + lane;
    comb[idx] += gv * (acc[h] / l[h]);   // stream-ordered accumulate
  }
}

extern "C" void kernel_launch(void* const* d_in, const int* in_sizes, int n_in,
                              void* d_out, int out_size, void* d_ws, size_t ws_size,
                              hipStream_t stream) {
  const float* x   = (const float*)d_in[0];
  const float* Wq  = (const float*)d_in[1];
  const float* Wk  = (const float*)d_in[2];
  const float* Wv  = (const float*)d_in[3];
  const float* Wo  = (const float*)d_in[4];
  const float* Wg  = (const float*)d_in[5];
  const float* Wck = (const float*)d_in[6];
  const float* Wcv = (const float*)d_in[7];
  float* out = (float*)d_out;
  float* ws = (float*)d_ws;

  float* qbuf = ws;                       // T*HQ*D        = 4,194,304
  float* kbuf = qbuf + 4194304;           // T*G*D         =   262,144
  float* vbuf = kbuf + 262144;            // T*G*D         =   262,144
  float* gr   = vbuf + 262144;            // T*3 (padded)  =     8,192
  float* ckb  = gr + 8192;                // C*G*D (pad)   =    16,384
  float* cvb  = ckb + 16384;              //               =    16,384
  unsigned* sel = (unsigned*)(cvb + 16384); // T*G uint    =     4,096
  float* comb = cvb + 16384 + 4096;       // T*HQ*D        = 4,194,304
  // total ~36 MB

  dim3 blk(16, 16);
  gemm_abt<<<dim3(32, 32), blk, 0, stream>>>(x, Wq, qbuf, 2048, 2048, 2048);
  gemm_abt<<<dim3(2, 32),  blk, 0, stream>>>(x, Wk, kbuf, 2048, 128, 2048);
  gemm_abt<<<dim3(2, 32),  blk, 0, stream>>>(x, Wv, vbuf, 2048, 128, 2048);
  gemm_abt<<<dim3(1, 32),  blk, 0, stream>>>(x, Wg, gr,   2048, 3,   2048);
  rope_all<<<2048, 256, 0, stream>>>(qbuf, kbuf);
  compress_kv<<<dim3(127, 2), 256, 0, stream>>>(kbuf, vbuf, Wck, Wcv, ckb, cvb);
  comp_attn<<<dim3(2048, 2), 128, 0, stream>>>(qbuf, ckb, cvb, gr, comb, sel);
  sel_attn<0><<<dim3(2048, 2), 256, 0, stream>>>(qbuf, kbuf, vbuf, gr, sel, comb);
  sel_attn<1><<<dim3(2048, 2), 256, 0, stream>>>(qbuf, kbuf, vbuf, gr, sel, comb);
  gemm_abt<<<dim3(32, 32), blk, 0, stream>>>(comb, Wo, out, 2048, 2048, 2048);
}

// Round 2
// 2890.891 us; speedup vs baseline: 1.2956x; 1.2956x over previous
//
#include <hip/hip_runtime.h>
#include <math.h>

#define T_SEQ 2048
#define NHQ 32
#define NG 2
#define HD 64
#define CSTRIDE 16
#define SCALE 0.125f

typedef __attribute__((ext_vector_type(8))) short short8_t;
typedef __attribute__((ext_vector_type(4))) float f32x4;

__device__ inline ushort f2bf(float x) {
  union { float f; unsigned u; } c; c.f = x;
  unsigned r = c.u + 0x7fff + ((c.u >> 16) & 1);
  return (ushort)(r >> 16);
}

// ---------------- GEMM: C[M,N] = A[M,K] * B[N,K]^T ----------------
__global__ __launch_bounds__(256) void gemm_abt(
    const float* __restrict__ A, const float* __restrict__ B,
    float* __restrict__ C, int M, int N, int K) {
  __shared__ __align__(16) float As[32][68];
  __shared__ __align__(16) float Bs[32][68];
  const int tx = threadIdx.x, ty = threadIdx.y;
  const int tid = ty * 16 + tx;
  const int m0 = blockIdx.y * 64, n0 = blockIdx.x * 64;
  float acc[4][4] = {};
  for (int k0 = 0; k0 < K; k0 += 32) {
    #pragma unroll
    for (int i = 0; i < 8; ++i) {
      int idx = tid + i * 256;
      int r = idx >> 5, kk = idx & 31;
      int gm = m0 + r, gn = n0 + r;
      As[kk][r] = (gm < M) ? A[(size_t)gm * K + k0 + kk] : 0.f;
      Bs[kk][r] = (gn < N) ? B[(size_t)gn * K + k0 + kk] : 0.f;
    }
    __syncthreads();
    #pragma unroll
    for (int kk = 0; kk < 32; ++kk) {
      float4 a4 = *reinterpret_cast<const float4*>(&As[kk][ty * 4]);
      float4 b4 = *reinterpret_cast<const float4*>(&Bs[kk][tx * 4]);
      float a_[4] = {a4.x, a4.y, a4.z, a4.w};
      float b_[4] = {b4.x, b4.y, b4.z, b4.w};
      #pragma unroll
      for (int i = 0; i < 4; ++i)
        #pragma unroll
        for (int j = 0; j < 4; ++j) acc[i][j] += a_[i] * b_[j];
    }
    __syncthreads();
  }
  #pragma unroll
  for (int i = 0; i < 4; ++i) {
    int gm = m0 + ty * 4 + i;
    if (gm >= M) continue;
    #pragma unroll
    for (int j = 0; j < 4; ++j) {
      int gn = n0 + tx * 4 + j;
      if (gn < N) C[(size_t)gm * N + gn] = acc[i][j];
    }
  }
}

// same but A = A1 + A2 elementwise (for final out-proj on comb1+comb2)
__global__ __launch_bounds__(256) void gemm_abt_sum2(
    const float* __restrict__ A1, const float* __restrict__ A2,
    const float* __restrict__ B, float* __restrict__ C, int M, int N, int K) {
  __shared__ __align__(16) float As[32][68];
  __shared__ __align__(16) float Bs[32][68];
  const int tx = threadIdx.x, ty = threadIdx.y;
  const int tid = ty * 16 + tx;
  const int m0 = blockIdx.y * 64, n0 = blockIdx.x * 64;
  float acc[4][4] = {};
  for (int k0 = 0; k0 < K; k0 += 32) {
    #pragma unroll
    for (int i = 0; i < 8; ++i) {
      int idx = tid + i * 256;
      int r = idx >> 5, kk = idx & 31;
      int gm = m0 + r, gn = n0 + r;
      size_t ai = (size_t)gm * K + k0 + kk;
      As[kk][r] = (gm < M) ? A1[ai] + A2[ai] : 0.f;
      Bs[kk][r] = (gn < N) ? B[(size_t)gn * K + k0 + kk] : 0.f;
    }
    __syncthreads();
    #pragma unroll
    for (int kk = 0; kk < 32; ++kk) {
      float4 a4 = *reinterpret_cast<const float4*>(&As[kk][ty * 4]);
      float4 b4 = *reinterpret_cast<const float4*>(&Bs[kk][tx * 4]);
      float a_[4] = {a4.x, a4.y, a4.z, a4.w};
      float b_[4] = {b4.x, b4.y, b4.z, b4.w};
      #pragma unroll
      for (int i = 0; i < 4; ++i)
        #pragma unroll
        for (int j = 0; j < 4; ++j) acc[i][j] += a_[i] * b_[j];
    }
    __syncthreads();
  }
  #pragma unroll
  for (int i = 0; i < 4; ++i) {
    int gm = m0 + ty * 4 + i;
    if (gm >= M) continue;
    #pragma unroll
    for (int j = 0; j < 4; ++j) {
      int gn = n0 + tx * 4 + j;
      if (gn < N) C[(size_t)gm * N + gn] = acc[i][j];
    }
  }
}

// ---------------- RoPE (in-place on q and k) ----------------
__global__ __launch_bounds__(256) void rope_all(float* __restrict__ q,
                                                float* __restrict__ k) {
  const int t = blockIdx.x;
  const float lnb_over = 9.210340371976184f / 32.f;  // ln(10000)/32
  for (int job = threadIdx.x; job < (NHQ + NG) * 32; job += 256) {
    int h = job >> 5, j = job & 31;
    float* base = (h < NHQ) ? (q + ((size_t)t * NHQ + h) * HD)
                            : (k + ((size_t)t * NG + (h - NHQ)) * HD);
    float inv = expf(-(float)j * lnb_over);
    float fr = (float)t * inv;
    float c_ = cosf(fr), s_ = sinf(fr);
    float x1 = base[j], x2 = base[j + 32];
    base[j] = x1 * c_ - x2 * s_;
    base[j + 32] = x2 * c_ + x1 * s_;
  }
}

// ---------------- fp32 -> bf16 converts ----------------
__global__ __launch_bounds__(256) void cvt_bf(const float* __restrict__ src,
                                              ushort* __restrict__ dst, int n) {
  int i = blockIdx.x * 256 + threadIdx.x;
  if (i < n) dst[i] = f2bf(src[i]);
}

// v[s][g][d] fp32 -> vt[g][d][s] bf16 (global transpose; tiny buffer)
__global__ __launch_bounds__(256) void cvt_vt(const float* __restrict__ v,
                                              ushort* __restrict__ vt) {
  int i = blockIdx.x * 256 + threadIdx.x;  // over T*G*D
  if (i >= T_SEQ * NG * HD) return;
  int d = i & 63, g = (i >> 6) & 1, s = i >> 7;
  vt[((size_t)g * HD + d) * T_SEQ + s] = f2bf(v[i]);
}

// ---------------- compression: ck/cv[c][g][d] ----------------
__global__ __launch_bounds__(256) void compress_kv(
    const float* __restrict__ k, const float* __restrict__ v,
    const float* __restrict__ Wck, const float* __restrict__ Wcv,
    float* __restrict__ ck, float* __restrict__ cv) {
  const int c = blockIdx.x, g = blockIdx.y;
  const int tid = threadIdx.x;
  const int d = tid & 63, chunk = tid >> 6;
  __shared__ float red[2][4][64];
  float ak = 0.f, av = 0.f;
  for (int f = chunk * 512; f < chunk * 512 + 512; ++f) {
    int i = f >> 6, e = f & 63;
    int trow = c * CSTRIDE + i;
    float kv = k[((size_t)trow * NG + g) * HD + e];
    float vv = v[((size_t)trow * NG + g) * HD + e];
    ak += kv * Wck[((size_t)g * 2048 + f) * HD + d];
    av += vv * Wcv[((size_t)g * 2048 + f) * HD + d];
  }
  red[0][chunk][d] = ak;
  red[1][chunk][d] = av;
  __syncthreads();
  if (tid < 64) {
    ck[((size_t)c * NG + g) * HD + tid] =
        red[0][0][tid] + red[0][1][tid] + red[0][2][tid] + red[0][3][tid];
  } else if (tid < 128) {
    int dd = tid - 64;
    cv[((size_t)c * NG + g) * HD + dd] =
        red[1][0][dd] + red[1][1][dd] + red[1][2][dd] + red[1][3][dd];
  }
}

// ------- compressed attention + block scores + top-16 selection -------
__global__ __launch_bounds__(128) void comp_attn(
    const float* __restrict__ q, const float* __restrict__ ck,
    const float* __restrict__ cv, const float* __restrict__ gr,
    float* __restrict__ comb, unsigned* __restrict__ sel) {
  const int t = blockIdx.x, g = blockIdx.y;
  const int tid = threadIdx.x;
  __shared__ float qs[16][64];
  __shared__ float p[16][128];
  __shared__ float sc[32];
  for (int i = tid; i < 1024; i += 128)
    qs[i >> 6][i & 63] = q[((size_t)t * NHQ + g * 16 + (i >> 6)) * HD + (i & 63)];
  __syncthreads();
  const int cmaxv = (t >= 31) ? min(126, (t - 31) >> 4) : -1;
  const int nv = cmaxv + 1;
  for (int h = 0; h < 16; ++h) {
    for (int c = tid; c < nv; c += 128) {
      const float* ckp = ck + ((size_t)c * NG + g) * HD;
      float acc = 0.f;
      #pragma unroll
      for (int e = 0; e < 64; ++e) acc += qs[h][e] * ckp[e];
      p[h][c] = acc * SCALE;
    }
  }
  __syncthreads();
  if (tid < 16) {
    const int h = tid;
    float mx = -INFINITY;
    for (int c = 0; c < nv; ++c) mx = fmaxf(mx, p[h][c]);
    float s = 0.f;
    for (int c = 0; c < nv; ++c) { float e_ = expf(p[h][c] - mx); p[h][c] = e_; s += e_; }
    float is = (nv > 0) ? 1.f / s : 0.f;
    for (int c = 0; c < nv; ++c) p[h][c] *= is;
  }
  __syncthreads();
  const float g0 = 1.f / (1.f + expf(-gr[t * 3 + 0]));
  for (int job = tid; job < 1024; job += 128) {
    int h = job >> 6, d = job & 63;
    float acc = 0.f;
    for (int c = 0; c < nv; ++c) acc += p[h][c] * cv[((size_t)c * NG + g) * HD + d];
    comb[((size_t)t * NHQ + g * 16 + h) * HD + d] = g0 * acc;
  }
  if (tid < 32) {
    const int b = tid, qb = t >> 6;
    float s;
    if (b > qb) s = -INFINITY;
    else if (b == 0 || qb - b < 2) s = INFINITY;
    else {
      s = 0.f;
      int clo = (4 * b - 1 > 0) ? 4 * b - 1 : 0;
      int chi = min(cmaxv, 4 * b + 3);
      for (int c = clo; c <= chi; ++c) {
        float cs_ = 0.f;
        for (int h = 0; h < 16; ++h) cs_ += p[h][c];
        s += cs_;
      }
    }
    sc[b] = s;
  }
  __syncthreads();
  if (tid == 0) {  // top-16, ties -> lowest index (matches jax.lax.top_k)
    unsigned m_ = 0;
    #pragma unroll 1
    for (int it = 0; it < 16; ++it) {
      float best = -INFINITY; int bi = -1;
      for (int b = 0; b < 32; ++b)
        if (sc[b] > best) { best = sc[b]; bi = b; }
      if (bi < 0) break;
      m_ |= 1u << bi;
      sc[bi] = -INFINITY;
    }
    sel[t * NG + g] = m_;
  }
}

__device__ inline float rowmax16(float x) {
  x = fmaxf(x, __shfl_xor(x, 1)); x = fmaxf(x, __shfl_xor(x, 2));
  x = fmaxf(x, __shfl_xor(x, 4)); x = fmaxf(x, __shfl_xor(x, 8));
  return x;
}
__device__ inline float rowsum16(float x) {
  x += __shfl_xor(x, 1); x += __shfl_xor(x, 2);
  x += __shfl_xor(x, 4); x += __shfl_xor(x, 8);
  return x;
}

// ------- MFMA flash attention: sparse (mode 0 -> comb1 +=) and
//         sliding-window (mode 1 -> comb2 =). Wave = 1 head x 64 queries.
__global__ __launch_bounds__(256) void mfma_attn(
    const ushort* __restrict__ qb16, const ushort* __restrict__ kb16,
    const ushort* __restrict__ vtb, const float* __restrict__ gr,
    const unsigned* __restrict__ sel, float* __restrict__ comb1,
    float* __restrict__ comb2) {
  const int qb = blockIdx.x, g = blockIdx.y;
  const int hg = blockIdx.z & 3, mode = blockIdx.z >> 2;
  const int tid = threadIdx.x, lane = tid & 63, w = tid >> 6;
  const int quad = lane >> 4, l16 = lane & 15;
  const int head = g * 16 + hg * 4 + w;
  const int t0 = qb * 64;

  __shared__ ushort pp[4][64][72];  // per-wave P tile, +8 pad (2-way = free)
  __shared__ unsigned sel_s[64];

  if (tid < 64) sel_s[tid] = sel[(size_t)(t0 + tid) * NG + g];
  __syncthreads();

  // Q A-frags: A[m=l16][k=quad*8+j]  (verified gemm_bt convention)
  short8_t aQ[4][2];
  #pragma unroll
  for (int mt = 0; mt < 4; ++mt)
    #pragma unroll
    for (int kt = 0; kt < 2; ++kt)
      aQ[mt][kt] = *(const short8_t*)(qb16 +
          ((size_t)(t0 + mt * 16 + l16) * NHQ + head) * HD + kt * 32 + quad * 8);

  float m_[4][4], l_[4][4];
  f32x4 acc_o[4][4];
  const f32x4 fz = {0.f, 0.f, 0.f, 0.f};
  #pragma unroll
  for (int mt = 0; mt < 4; ++mt)
    #pragma unroll
    for (int r = 0; r < 4; ++r) { m_[mt][r] = -INFINITY; l_[mt][r] = 0.f; }
  #pragma unroll
  for (int mt = 0; mt < 4; ++mt)
    #pragma unroll
    for (int dt = 0; dt < 4; ++dt) acc_o[mt][dt] = fz;

  unsigned mrem = 0; int b0 = 0, nb;
  if (mode == 0) {
    unsigned uni = 0;
    for (int i = 0; i < 64; ++i) uni |= sel_s[i];  // broadcast reads
    mrem = uni; nb = __popc(uni);
  } else {
    b0 = (qb > 8) ? qb - 8 : 0; nb = qb - b0 + 1;
  }

  for (int ib = 0; ib < nb; ++ib) {
    int blk;
    if (mode == 0) { blk = __ffs(mrem) - 1; mrem &= mrem - 1; } else { blk = b0 + ib; }

    // ---- S = Q K^T (32 MFMAs) ----
    f32x4 sacc[4][4];
    #pragma unroll
    for (int nt = 0; nt < 4; ++nt) {
      const ushort* kr = kb16 +
          ((size_t)(blk * 64 + nt * 16 + l16) * NG + g) * HD + quad * 8;
      short8_t bk0 = *(const short8_t*)kr;
      short8_t bk1 = *(const short8_t*)(kr + 32);
      #pragma unroll
      for (int mt = 0; mt < 4; ++mt) {
        f32x4 c = __builtin_amdgcn_mfma_f32_16x16x32_bf16(aQ[mt][0], bk0, fz, 0, 0, 0);
        sacc[mt][nt] = __builtin_amdgcn_mfma_f32_16x16x32_bf16(aQ[mt][1], bk1, c, 0, 0, 0);
      }
    }

    // ---- mask + online softmax (C-layout: row=quad*4+r, col=l16) ----
    #pragma unroll
    for (int mt = 0; mt < 4; ++mt) {
      #pragma unroll
      for (int r = 0; r < 4; ++r) {
        const int q_l = mt * 16 + quad * 4 + r;
        const int qg = t0 + q_l;
        const unsigned sbits = sel_s[q_l];
        float sv[4];
        float mx = -INFINITY;
        #pragma unroll
        for (int nt = 0; nt < 4; ++nt) {
          int key = blk * 64 + nt * 16 + l16;
          bool ok = (key <= qg) &&
                    (mode == 0 ? (((sbits >> blk) & 1u) != 0) : (qg - key <= 512));
          float s_ = ok ? sacc[mt][nt][r] * SCALE : -1e30f;
          sv[nt] = s_;
          mx = fmaxf(mx, s_);
        }
        mx = rowmax16(mx);
        float mnew = fmaxf(m_[mt][r], mx);
        float alpha = __expf(m_[mt][r] - mnew);
        float rsum = 0.f;
        #pragma unroll
        for (int nt = 0; nt < 4; ++nt) {
          float p = __expf(sv[nt] - mnew);
          rsum += p;
          pp[w][q_l][nt * 16 + l16] = f2bf(p);
        }
        rsum = rowsum16(rsum);
        l_[mt][r] = l_[mt][r] * alpha + rsum;
        m_[mt][r] = mnew;
        #pragma unroll
        for (int dt = 0; dt < 4; ++dt) acc_o[mt][dt][r] *= alpha;
      }
    }

    // ---- O += P V (32 MFMAs); P via LDS C->A transpose, V from global vt ----
    short8_t aP[4][2];
    #pragma unroll
    for (int mt = 0; mt < 4; ++mt)
      #pragma unroll
      for (int kt = 0; kt < 2; ++kt)
        aP[mt][kt] = *(const short8_t*)&pp[w][mt * 16 + l16][kt * 32 + quad * 8];
    #pragma unroll
    for (int dt = 0; dt < 4; ++dt) {
      const ushort* vr = vtb + ((size_t)g * HD + dt * 16 + l16) * T_SEQ +
                         blk * 64 + quad * 8;
      short8_t bv0 = *(const short8_t*)vr;
      short8_t bv1 = *(const short8_t*)(vr + 32);
      #pragma unroll
      for (int mt = 0; mt < 4; ++mt) {
        acc_o[mt][dt] = __builtin_amdgcn_mfma_f32_16x16x32_bf16(aP[mt][0], bv0, acc_o[mt][dt], 0, 0, 0);
        acc_o[mt][dt] = __builtin_amdgcn_mfma_f32_16x16x32_bf16(aP[mt][1], bv1, acc_o[mt][dt], 0, 0, 0);
      }
    }
  }

  // ---- epilogue: gate * O/l into comb ----
  #pragma unroll
  for (int mt = 0; mt < 4; ++mt) {
    #pragma unroll
    for (int r = 0; r < 4; ++r) {
      const int t = t0 + mt * 16 + quad * 4 + r;
      const float c_ = (1.f / (1.f + __expf(-gr[t * 3 + 1 + mode]))) / l_[mt][r];
      #pragma unroll
      for (int dt = 0; dt < 4; ++dt) {
        size_t idx = ((size_t)t * NHQ + head) * HD + dt * 16 + l16;
        if (mode == 0) comb1[idx] += c_ * acc_o[mt][dt][r];
        else           comb2[idx]  = c_ * acc_o[mt][dt][r];
      }
    }
  }
}

extern "C" void kernel_launch(void* const* d_in, const int* in_sizes, int n_in,
                              void* d_out, int out_size, void* d_ws, size_t ws_size,
                              hipStream_t stream) {
  const float* x   = (const float*)d_in[0];
  const float* Wq  = (const float*)d_in[1];
  const float* Wk  = (const float*)d_in[2];
  const float* Wv  = (const float*)d_in[3];
  const float* Wo  = (const float*)d_in[4];
  const float* Wg  = (const float*)d_in[5];
  const float* Wck = (const float*)d_in[6];
  const float* Wcv = (const float*)d_in[7];
  float* out = (float*)d_out;
  float* ws = (float*)d_ws;

  float* qbuf = ws;                         // 4,194,304 f
  float* kbuf = qbuf + 4194304;             //   262,144 f
  float* vbuf = kbuf + 262144;              //   262,144 f
  float* gr   = vbuf + 262144;              //     8,192 f
  float* ckb  = gr + 8192;                  //    16,384 f
  float* cvb  = ckb + 16384;                //    16,384 f
  unsigned* sel = (unsigned*)(cvb + 16384); //     4,096
  float* comb1 = cvb + 16384 + 4096;        // 4,194,304 f
  ushort* qbf = (ushort*)(comb1 + 4194304); // 4,194,304 u16
  ushort* kbf = qbf + 4194304;              //   262,144 u16
  ushort* vtb = kbf + 262144;               //   262,144 u16
  float* comb2 = qbuf;  // alias: fp32 q dead once comp_attn+cvt done (stream-ordered)
  // total ~45.3 MB

  dim3 blk(16, 16);
  gemm_abt<<<dim3(32, 32), blk, 0, stream>>>(x, Wq, qbuf, 2048, 2048, 2048);
  gemm_abt<<<dim3(2, 32),  blk, 0, stream>>>(x, Wk, kbuf, 2048, 128, 2048);
  gemm_abt<<<dim3(2, 32),  blk, 0, stream>>>(x, Wv, vbuf, 2048, 128, 2048);
  gemm_abt<<<dim3(1, 32),  blk, 0, stream>>>(x, Wg, gr,   2048, 3,   2048);
  rope_all<<<2048, 256, 0, stream>>>(qbuf, kbuf);
  cvt_bf<<<(4194304 + 255) / 256, 256, 0, stream>>>(qbuf, qbf, 4194304);
  cvt_bf<<<(262144 + 255) / 256, 256, 0, stream>>>(kbuf, kbf, 262144);
  cvt_vt<<<(262144 + 255) / 256, 256, 0, stream>>>(vbuf, vtb);
  compress_kv<<<dim3(127, 2), 256, 0, stream>>>(kbuf, vbuf, Wck, Wcv, ckb, cvb);
  comp_attn<<<dim3(2048, 2), 128, 0, stream>>>(qbuf, ckb, cvb, gr, comb1, sel);
  mfma_attn<<<dim3(32, 2, 8), 256, 0, stream>>>(qbf, kbf, vtb, gr, sel, comb1, comb2);
  gemm_abt_sum2<<<dim3(32, 32), blk, 0, stream>>>(comb1, comb2, Wo, out, 2048, 2048, 2048);
}

// Round 3
// 912.926 us; speedup vs baseline: 4.1026x; 3.1666x over previous
//
#include <hip/hip_runtime.h>
#include <math.h>

#define T_SEQ 2048
#define NHQ 32
#define NG 2
#define HD 64
#define CSTRIDE 16
#define SCALE 0.125f
#define KVGW 384  // fused k|v|gate row width: 128 k + 128 v + 3 gate + pad

typedef __attribute__((ext_vector_type(8))) short short8_t;
typedef __attribute__((ext_vector_type(4))) float f32x4;

__device__ __forceinline__ ushort f2bf(float x) {
  union { float f; unsigned u; } c; c.f = x;
  unsigned r = c.u + 0x7fff + ((c.u >> 16) & 1);
  return (ushort)(r >> 16);
}

__device__ __forceinline__ void glds16(const ushort* g, ushort* l) {
  __builtin_amdgcn_global_load_lds(
      (const __attribute__((address_space(1))) unsigned int*)g,
      (__attribute__((address_space(3))) unsigned int*)l, 16, 0, 0);
}

// ---- bf16 MFMA GEMM: C[M,N] = A[M,K] * B[N,K]^T, all dims %128 (N%128 ok via pad)
// 128x128 tile, BK=64, 4 waves each 64x64. XOR-swizzled LDS chunks -> no bank
// conflicts on ds_read_b128; global_load_lds width=16 staging (m97 recipe).
__global__ __launch_bounds__(256) void mgemm(
    const ushort* __restrict__ A, const ushort* __restrict__ B,
    float* __restrict__ C, int M, int N, int K) {
  __shared__ __align__(16) ushort As[128 * 64];
  __shared__ __align__(16) ushort Bs[128 * 64];
  const int tid = threadIdx.x;
  const int lane = tid & 63, w = tid >> 6;
  const int quad = lane >> 4, l16 = lane & 15;
  const int m0 = blockIdx.y * 128, n0 = blockIdx.x * 128;
  const int mq = (w & 1) * 64, nq = (w >> 1) * 64;
  f32x4 acc[4][4];
  const f32x4 fz = {0.f, 0.f, 0.f, 0.f};
  #pragma unroll
  for (int i = 0; i < 4; ++i)
    #pragma unroll
    for (int j = 0; j < 4; ++j) acc[i][j] = fz;

  for (int k0 = 0; k0 < K; k0 += 64) {
    __syncthreads();  // previous iter's readers done
    #pragma unroll
    for (int j = 0; j < 4; ++j) {
      int ci = j * 256 + tid;       // chunk index 0..1023 (16B chunks)
      int row = ci >> 3, cl = ci & 7;
      int kc = cl ^ (row & 7);      // swizzle applied at global source
      glds16(A + ((size_t)(m0 + row) * K + k0 + kc * 8), &As[ci * 8]);
      glds16(B + ((size_t)(n0 + row) * K + k0 + kc * 8), &Bs[ci * 8]);
    }
    __syncthreads();  // staging complete (vmcnt drained by barrier)
    #pragma unroll
    for (int kt = 0; kt < 2; ++kt) {
      short8_t af[4], bf_[4];
      #pragma unroll
      for (int mt = 0; mt < 4; ++mt) {
        int row = mq + mt * 16 + l16;
        int cl = (kt * 4 + quad) ^ (row & 7);
        af[mt] = *(const short8_t*)&As[row * 64 + cl * 8];
      }
      #pragma unroll
      for (int nt = 0; nt < 4; ++nt) {
        int row = nq + nt * 16 + l16;
        int cl = (kt * 4 + quad) ^ (row & 7);
        bf_[nt] = *(const short8_t*)&Bs[row * 64 + cl * 8];
      }
      #pragma unroll
      for (int mt = 0; mt < 4; ++mt)
        #pragma unroll
        for (int nt = 0; nt < 4; ++nt)
          acc[mt][nt] = __builtin_amdgcn_mfma_f32_16x16x32_bf16(
              af[mt], bf_[nt], acc[mt][nt], 0, 0, 0);
    }
  }
  #pragma unroll
  for (int mt = 0; mt < 4; ++mt)
    #pragma unroll
    for (int nt = 0; nt < 4; ++nt)
      #pragma unroll
      for (int r = 0; r < 4; ++r) {
        int m = m0 + mq + mt * 16 + quad * 4 + r;
        int n = n0 + nq + nt * 16 + l16;
        C[(size_t)m * N + n] = acc[mt][nt][r];
      }
}

// ---------------- conversions / packing ----------------
__global__ __launch_bounds__(256) void cvt_bf(const float* __restrict__ src,
                                              ushort* __restrict__ dst, int n) {
  int i = blockIdx.x * 256 + threadIdx.x;
  if (i < n) dst[i] = f2bf(src[i]);
}

__global__ __launch_bounds__(256) void cvt_sum2_bf(const float* __restrict__ a,
                                                   const float* __restrict__ b,
                                                   ushort* __restrict__ dst, int n) {
  int i = blockIdx.x * 256 + threadIdx.x;
  if (i < n) dst[i] = f2bf(a[i] + b[i]);
}

// pack Wk|Wv|Wgate (+zero pad) into wkvgb[KVGW][2048] bf16
__global__ __launch_bounds__(256) void pack_wkvg(
    const float* __restrict__ Wk, const float* __restrict__ Wv,
    const float* __restrict__ Wg, ushort* __restrict__ dst) {
  int i = blockIdx.x * 256 + threadIdx.x;
  if (i >= KVGW * 2048) return;
  int n = i >> 11, k = i & 2047;
  float v;
  if (n < 128) v = Wk[(size_t)n * 2048 + k];
  else if (n < 256) v = Wv[(size_t)(n - 128) * 2048 + k];
  else if (n < 259) v = Wg[(size_t)(n - 256) * 2048 + k];
  else v = 0.f;
  dst[i] = f2bf(v);
}

// kbf[t][g][d] bf16 from kvg
__global__ __launch_bounds__(256) void cvt_k(const float* __restrict__ kvg,
                                             ushort* __restrict__ kbf) {
  int i = blockIdx.x * 256 + threadIdx.x;  // over T*128
  if (i >= T_SEQ * 128) return;
  int gd = i & 127, t = i >> 7;
  kbf[i] = f2bf(kvg[(size_t)t * KVGW + gd]);
}

// vt[g][d][s] bf16 from kvg v-part
__global__ __launch_bounds__(256) void cvt_vt(const float* __restrict__ kvg,
                                              ushort* __restrict__ vt) {
  int i = blockIdx.x * 256 + threadIdx.x;  // over T*G*D
  if (i >= T_SEQ * NG * HD) return;
  int d = i & 63, g = (i >> 6) & 1, s = i >> 7;
  vt[((size_t)g * HD + d) * T_SEQ + s] =
      f2bf(kvg[(size_t)s * KVGW + 128 + g * 64 + d]);
}

// ---------------- RoPE (in-place on q and kvg's k-part) ----------------
__global__ __launch_bounds__(256) void rope_all(float* __restrict__ q,
                                                float* __restrict__ kvg) {
  const int t = blockIdx.x;
  const float lnb_over = 9.210340371976184f / 32.f;  // ln(10000)/32
  for (int job = threadIdx.x; job < (NHQ + NG) * 32; job += 256) {
    int h = job >> 5, j = job & 31;
    float* base = (h < NHQ) ? (q + ((size_t)t * NHQ + h) * HD)
                            : (kvg + (size_t)t * KVGW + (h - NHQ) * 64);
    float inv = expf(-(float)j * lnb_over);
    float fr = (float)t * inv;
    float c_ = cosf(fr), s_ = sinf(fr);
    float x1 = base[j], x2 = base[j + 32];
    base[j] = x1 * c_ - x2 * s_;
    base[j + 32] = x2 * c_ + x1 * s_;
  }
}

// ---------------- compression: ck/cv[c][g][d] ----------------
__global__ __launch_bounds__(256) void compress_kv(
    const float* __restrict__ kvg,
    const float* __restrict__ Wck, const float* __restrict__ Wcv,
    float* __restrict__ ck, float* __restrict__ cv) {
  const int c = blockIdx.x, g = blockIdx.y;
  const int tid = threadIdx.x;
  const int d = tid & 63, chunk = tid >> 6;
  __shared__ float red[2][4][64];
  float ak = 0.f, av = 0.f;
  for (int f = chunk * 512; f < chunk * 512 + 512; ++f) {
    int i = f >> 6, e = f & 63;
    int trow = c * CSTRIDE + i;
    float kv = kvg[(size_t)trow * KVGW + g * 64 + e];
    float vv = kvg[(size_t)trow * KVGW + 128 + g * 64 + e];
    ak += kv * Wck[((size_t)g * 2048 + f) * HD + d];
    av += vv * Wcv[((size_t)g * 2048 + f) * HD + d];
  }
  red[0][chunk][d] = ak;
  red[1][chunk][d] = av;
  __syncthreads();
  if (tid < 64) {
    ck[((size_t)c * NG + g) * HD + tid] =
        red[0][0][tid] + red[0][1][tid] + red[0][2][tid] + red[0][3][tid];
  } else if (tid < 128) {
    int dd = tid - 64;
    cv[((size_t)c * NG + g) * HD + dd] =
        red[1][0][dd] + red[1][1][dd] + red[1][2][dd] + red[1][3][dd];
  }
}

// ------- compressed attention + block scores + top-16 selection -------
__global__ __launch_bounds__(128) void comp_attn(
    const float* __restrict__ q, const float* __restrict__ ck,
    const float* __restrict__ cv, const float* __restrict__ kvg,
    float* __restrict__ comb, unsigned* __restrict__ sel) {
  const int t = blockIdx.x, g = blockIdx.y;
  const int tid = threadIdx.x;
  __shared__ float qs[16][64];
  __shared__ float p[16][128];
  __shared__ float sc[32];
  for (int i = tid; i < 1024; i += 128)
    qs[i >> 6][i & 63] = q[((size_t)t * NHQ + g * 16 + (i >> 6)) * HD + (i & 63)];
  __syncthreads();
  const int cmaxv = (t >= 31) ? min(126, (t - 31) >> 4) : -1;
  const int nv = cmaxv + 1;
  for (int h = 0; h < 16; ++h) {
    for (int c = tid; c < nv; c += 128) {
      const float* ckp = ck + ((size_t)c * NG + g) * HD;
      float acc = 0.f;
      #pragma unroll
      for (int e = 0; e < 64; ++e) acc += qs[h][e] * ckp[e];
      p[h][c] = acc * SCALE;
    }
  }
  __syncthreads();
  if (tid < 16) {
    const int h = tid;
    float mx = -INFINITY;
    for (int c = 0; c < nv; ++c) mx = fmaxf(mx, p[h][c]);
    float s = 0.f;
    for (int c = 0; c < nv; ++c) { float e_ = expf(p[h][c] - mx); p[h][c] = e_; s += e_; }
    float is = (nv > 0) ? 1.f / s : 0.f;
    for (int c = 0; c < nv; ++c) p[h][c] *= is;
  }
  __syncthreads();
  const float g0 = 1.f / (1.f + expf(-kvg[(size_t)t * KVGW + 256]));
  for (int job = tid; job < 1024; job += 128) {
    int h = job >> 6, d = job & 63;
    float acc = 0.f;
    for (int c = 0; c < nv; ++c) acc += p[h][c] * cv[((size_t)c * NG + g) * HD + d];
    comb[((size_t)t * NHQ + g * 16 + h) * HD + d] = g0 * acc;
  }
  if (tid < 32) {
    const int b = tid, qb = t >> 6;
    float s;
    if (b > qb) s = -INFINITY;
    else if (b == 0 || qb - b < 2) s = INFINITY;
    else {
      s = 0.f;
      int clo = (4 * b - 1 > 0) ? 4 * b - 1 : 0;
      int chi = min(cmaxv, 4 * b + 3);
      for (int c = clo; c <= chi; ++c) {
        float cs_ = 0.f;
        for (int h = 0; h < 16; ++h) cs_ += p[h][c];
        s += cs_;
      }
    }
    sc[b] = s;
  }
  __syncthreads();
  if (tid == 0) {  // top-16, ties -> lowest index (matches jax.lax.top_k)
    unsigned m_ = 0;
    #pragma unroll 1
    for (int it = 0; it < 16; ++it) {
      float best = -INFINITY; int bi = -1;
      for (int b = 0; b < 32; ++b)
        if (sc[b] > best) { best = sc[b]; bi = b; }
      if (bi < 0) break;
      m_ |= 1u << bi;
      sc[bi] = -INFINITY;
    }
    sel[t * NG + g] = m_;
  }
}

__device__ __forceinline__ float rowmax16(float x) {
  x = fmaxf(x, __shfl_xor(x, 1)); x = fmaxf(x, __shfl_xor(x, 2));
  x = fmaxf(x, __shfl_xor(x, 4)); x = fmaxf(x, __shfl_xor(x, 8));
  return x;
}
__device__ __forceinline__ float rowsum16(float x) {
  x += __shfl_xor(x, 1); x += __shfl_xor(x, 2);
  x += __shfl_xor(x, 4); x += __shfl_xor(x, 8);
  return x;
}

// ------- MFMA flash attention: sparse (mode 0 -> comb1 +=) and
//         sliding-window (mode 1 -> comb2 =). Wave = 1 head x 64 queries.
__global__ __launch_bounds__(256) void mfma_attn(
    const ushort* __restrict__ qb16, const ushort* __restrict__ kb16,
    const ushort* __restrict__ vtb, const float* __restrict__ kvg,
    const unsigned* __restrict__ sel, float* __restrict__ comb1,
    float* __restrict__ comb2) {
  const int qb = blockIdx.x, g = blockIdx.y;
  const int hg = blockIdx.z & 3, mode = blockIdx.z >> 2;
  const int tid = threadIdx.x, lane = tid & 63, w = tid >> 6;
  const int quad = lane >> 4, l16 = lane & 15;
  const int head = g * 16 + hg * 4 + w;
  const int t0 = qb * 64;

  __shared__ ushort pp[4][64][72];
  __shared__ unsigned sel_s[64];

  if (tid < 64) sel_s[tid] = sel[(size_t)(t0 + tid) * NG + g];
  __syncthreads();

  short8_t aQ[4][2];
  #pragma unroll
  for (int mt = 0; mt < 4; ++mt)
    #pragma unroll
    for (int kt = 0; kt < 2; ++kt)
      aQ[mt][kt] = *(const short8_t*)(qb16 +
          ((size_t)(t0 + mt * 16 + l16) * NHQ + head) * HD + kt * 32 + quad * 8);

  float m_[4][4], l_[4][4];
  f32x4 acc_o[4][4];
  const f32x4 fz = {0.f, 0.f, 0.f, 0.f};
  #pragma unroll
  for (int mt = 0; mt < 4; ++mt)
    #pragma unroll
    for (int r = 0; r < 4; ++r) { m_[mt][r] = -INFINITY; l_[mt][r] = 0.f; }
  #pragma unroll
  for (int mt = 0; mt < 4; ++mt)
    #pragma unroll
    for (int dt = 0; dt < 4; ++dt) acc_o[mt][dt] = fz;

  unsigned mrem = 0; int b0 = 0, nb;
  if (mode == 0) {
    unsigned uni = 0;
    for (int i = 0; i < 64; ++i) uni |= sel_s[i];
    mrem = uni; nb = __popc(uni);
  } else {
    b0 = (qb > 8) ? qb - 8 : 0; nb = qb - b0 + 1;
  }

  for (int ib = 0; ib < nb; ++ib) {
    int blk;
    if (mode == 0) { blk = __ffs(mrem) - 1; mrem &= mrem - 1; } else { blk = b0 + ib; }

    f32x4 sacc[4][4];
    #pragma unroll
    for (int nt = 0; nt < 4; ++nt) {
      const ushort* kr = kb16 +
          ((size_t)(blk * 64 + nt * 16 + l16) * NG + g) * HD + quad * 8;
      short8_t bk0 = *(const short8_t*)kr;
      short8_t bk1 = *(const short8_t*)(kr + 32);
      #pragma unroll
      for (int mt = 0; mt < 4; ++mt) {
        f32x4 c = __builtin_amdgcn_mfma_f32_16x16x32_bf16(aQ[mt][0], bk0, fz, 0, 0, 0);
        sacc[mt][nt] = __builtin_amdgcn_mfma_f32_16x16x32_bf16(aQ[mt][1], bk1, c, 0, 0, 0);
      }
    }

    #pragma unroll
    for (int mt = 0; mt < 4; ++mt) {
      #pragma unroll
      for (int r = 0; r < 4; ++r) {
        const int q_l = mt * 16 + quad * 4 + r;
        const int qg = t0 + q_l;
        const unsigned sbits = sel_s[q_l];
        float sv[4];
        float mx = -INFINITY;
        #pragma unroll
        for (int nt = 0; nt < 4; ++nt) {
          int key = blk * 64 + nt * 16 + l16;
          bool ok = (key <= qg) &&
                    (mode == 0 ? (((sbits >> blk) & 1u) != 0) : (qg - key <= 512));
          float s_ = ok ? sacc[mt][nt][r] * SCALE : -1e30f;
          sv[nt] = s_;
          mx = fmaxf(mx, s_);
        }
        mx = rowmax16(mx);
        float mnew = fmaxf(m_[mt][r], mx);
        float alpha = __expf(m_[mt][r] - mnew);
        float rsum = 0.f;
        #pragma unroll
        for (int nt = 0; nt < 4; ++nt) {
          float p = __expf(sv[nt] - mnew);
          rsum += p;
          pp[w][q_l][nt * 16 + l16] = f2bf(p);
        }
        rsum = rowsum16(rsum);
        l_[mt][r] = l_[mt][r] * alpha + rsum;
        m_[mt][r] = mnew;
        #pragma unroll
        for (int dt = 0; dt < 4; ++dt) acc_o[mt][dt][r] *= alpha;
      }
    }

    short8_t aP[4][2];
    #pragma unroll
    for (int mt = 0; mt < 4; ++mt)
      #pragma unroll
      for (int kt = 0; kt < 2; ++kt)
        aP[mt][kt] = *(const short8_t*)&pp[w][mt * 16 + l16][kt * 32 + quad * 8];
    #pragma unroll
    for (int dt = 0; dt < 4; ++dt) {
      const ushort* vr = vtb + ((size_t)g * HD + dt * 16 + l16) * T_SEQ +
                         blk * 64 + quad * 8;
      short8_t bv0 = *(const short8_t*)vr;
      short8_t bv1 = *(const short8_t*)(vr + 32);
      #pragma unroll
      for (int mt = 0; mt < 4; ++mt) {
        acc_o[mt][dt] = __builtin_amdgcn_mfma_f32_16x16x32_bf16(aP[mt][0], bv0, acc_o[mt][dt], 0, 0, 0);
        acc_o[mt][dt] = __builtin_amdgcn_mfma_f32_16x16x32_bf16(aP[mt][1], bv1, acc_o[mt][dt], 0, 0, 0);
      }
    }
  }

  #pragma unroll
  for (int mt = 0; mt < 4; ++mt) {
    #pragma unroll
    for (int r = 0; r < 4; ++r) {
      const int t = t0 + mt * 16 + quad * 4 + r;
      const float c_ =
          (1.f / (1.f + __expf(-kvg[(size_t)t * KVGW + 257 + mode]))) / l_[mt][r];
      #pragma unroll
      for (int dt = 0; dt < 4; ++dt) {
        size_t idx = ((size_t)t * NHQ + head) * HD + dt * 16 + l16;
        if (mode == 0) comb1[idx] += c_ * acc_o[mt][dt][r];
        else           comb2[idx]  = c_ * acc_o[mt][dt][r];
      }
    }
  }
}

extern "C" void kernel_launch(void* const* d_in, const int* in_sizes, int n_in,
                              void* d_out, int out_size, void* d_ws, size_t ws_size,
                              hipStream_t stream) {
  const float* x   = (const float*)d_in[0];
  const float* Wq  = (const float*)d_in[1];
  const float* Wk  = (const float*)d_in[2];
  const float* Wv  = (const float*)d_in[3];
  const float* Wo  = (const float*)d_in[4];
  const float* Wg  = (const float*)d_in[5];
  const float* Wck = (const float*)d_in[6];
  const float* Wcv = (const float*)d_in[7];
  float* out = (float*)d_out;
  float* ws = (float*)d_ws;

  // ---- workspace map (float slots) ----
  float* qbuf  = ws;                      // 4,194,304 f  (later comb2 fp32, then wob u16)
  float* comb1 = qbuf + 4194304;          // 4,194,304 f
  float* kvg   = comb1 + 4194304;         //   786,432 f
  float* ckb   = kvg + 786432;            //    16,384 f
  float* cvb   = ckb + 16384;             //    16,384 f
  unsigned* sel = (unsigned*)(cvb + 16384);  //  4,096 u32
  ushort* kbf  = (ushort*)(cvb + 16384 + 4096);  // 262,144 u16 (131,072 f)
  ushort* vtb  = kbf + 262144;            // 262,144 u16
  ushort* wkvgb = vtb + 262144;           // 786,432 u16 (393,216 f)
  ushort* regA = wkvgb + 786432;          // 4,194,304 u16: xb -> combb
  ushort* regB = regA + 4194304;          // 4,194,304 u16: wqb -> qbf
  // total ~56.2 MB
  ushort* xb = regA;      ushort* combb = regA;
  ushort* wqb = regB;     ushort* qbf = regB;
  float* comb2 = qbuf;                    // alias: fp32 q dead after comp_attn
  ushort* wob = (ushort*)qbuf;            // alias: created after cvt_sum2

  const int CV = (4194304 + 255) / 256;
  cvt_bf<<<CV, 256, 0, stream>>>(x, xb, 4194304);
  cvt_bf<<<CV, 256, 0, stream>>>(Wq, wqb, 4194304);
  pack_wkvg<<<(KVGW * 2048 + 255) / 256, 256, 0, stream>>>(Wk, Wv, Wg, wkvgb);

  mgemm<<<dim3(16, 16), 256, 0, stream>>>(xb, wqb, qbuf, 2048, 2048, 2048);
  mgemm<<<dim3(3, 16), 256, 0, stream>>>(xb, wkvgb, kvg, 2048, KVGW, 2048);

  rope_all<<<2048, 256, 0, stream>>>(qbuf, kvg);
  cvt_bf<<<CV, 256, 0, stream>>>(qbuf, qbf, 4194304);  // regB: wqb dead
  cvt_k<<<(262144 + 255) / 256, 256, 0, stream>>>(kvg, kbf);
  cvt_vt<<<(262144 + 255) / 256, 256, 0, stream>>>(kvg, vtb);
  compress_kv<<<dim3(127, 2), 256, 0, stream>>>(kvg, Wck, Wcv, ckb, cvb);
  comp_attn<<<dim3(2048, 2), 128, 0, stream>>>(qbuf, ckb, cvb, kvg, comb1, sel);
  mfma_attn<<<dim3(32, 2, 8), 256, 0, stream>>>(qbf, kbf, vtb, kvg, sel, comb1, comb2);

  cvt_sum2_bf<<<CV, 256, 0, stream>>>(comb1, comb2, combb, 4194304);  // regA: xb dead
  cvt_bf<<<CV, 256, 0, stream>>>(Wo, wob, 4194304);                   // qbuf region dead
  mgemm<<<dim3(16, 16), 256, 0, stream>>>(combb, wob, out, 2048, 2048, 2048);
}

// Round 4
// 740.816 us; speedup vs baseline: 5.0557x; 1.2323x over previous
//
#include <hip/hip_runtime.h>
#include <math.h>

#define T_SEQ 2048
#define NHQ 32
#define NG 2
#define HD 64
#define CSTRIDE 16
#define SCALE 0.125f
#define KVGW 384  // fused k|v|gate row width: 128 k + 128 v + 3 gate + pad

typedef __attribute__((ext_vector_type(8))) short short8_t;
typedef __attribute__((ext_vector_type(4))) short short4_t;
typedef __attribute__((ext_vector_type(4))) float f32x4;

__device__ __forceinline__ ushort f2bf(float x) {
  union { float f; unsigned u; } c; c.f = x;
  unsigned r = c.u + 0x7fff + ((c.u >> 16) & 1);
  return (ushort)(r >> 16);
}

__device__ __forceinline__ void glds16(const ushort* g, ushort* l) {
  __builtin_amdgcn_global_load_lds(
      (const __attribute__((address_space(1))) unsigned int*)g,
      (__attribute__((address_space(3))) unsigned int*)l, 16, 0, 0);
}

// ---- bf16 MFMA GEMM: C[M,N] = A[M,K] * B[N,K]^T, all dims %128 (N%128 ok via pad)
// 128x128 tile, BK=64, 4 waves each 64x64. XOR-swizzled LDS chunks -> no bank
// conflicts on ds_read_b128; global_load_lds width=16 staging (m97 recipe).
__global__ __launch_bounds__(256) void mgemm(
    const ushort* __restrict__ A, const ushort* __restrict__ B,
    float* __restrict__ C, int M, int N, int K) {
  __shared__ __align__(16) ushort As[128 * 64];
  __shared__ __align__(16) ushort Bs[128 * 64];
  const int tid = threadIdx.x;
  const int lane = tid & 63, w = tid >> 6;
  const int quad = lane >> 4, l16 = lane & 15;
  const int m0 = blockIdx.y * 128, n0 = blockIdx.x * 128;
  const int mq = (w & 1) * 64, nq = (w >> 1) * 64;
  f32x4 acc[4][4];
  const f32x4 fz = {0.f, 0.f, 0.f, 0.f};
  #pragma unroll
  for (int i = 0; i < 4; ++i)
    #pragma unroll
    for (int j = 0; j < 4; ++j) acc[i][j] = fz;

  for (int k0 = 0; k0 < K; k0 += 64) {
    __syncthreads();
    #pragma unroll
    for (int j = 0; j < 4; ++j) {
      int ci = j * 256 + tid;       // chunk index 0..1023 (16B chunks)
      int row = ci >> 3, cl = ci & 7;
      int kc = cl ^ (row & 7);      // swizzle applied at global source
      glds16(A + ((size_t)(m0 + row) * K + k0 + kc * 8), &As[ci * 8]);
      glds16(B + ((size_t)(n0 + row) * K + k0 + kc * 8), &Bs[ci * 8]);
    }
    __syncthreads();
    #pragma unroll
    for (int kt = 0; kt < 2; ++kt) {
      short8_t af[4], bf_[4];
      #pragma unroll
      for (int mt = 0; mt < 4; ++mt) {
        int row = mq + mt * 16 + l16;
        int cl = (kt * 4 + quad) ^ (row & 7);
        af[mt] = *(const short8_t*)&As[row * 64 + cl * 8];
      }
      #pragma unroll
      for (int nt = 0; nt < 4; ++nt) {
        int row = nq + nt * 16 + l16;
        int cl = (kt * 4 + quad) ^ (row & 7);
        bf_[nt] = *(const short8_t*)&Bs[row * 64 + cl * 8];
      }
      #pragma unroll
      for (int mt = 0; mt < 4; ++mt)
        #pragma unroll
        for (int nt = 0; nt < 4; ++nt)
          acc[mt][nt] = __builtin_amdgcn_mfma_f32_16x16x32_bf16(
              af[mt], bf_[nt], acc[mt][nt], 0, 0, 0);
    }
  }
  #pragma unroll
  for (int mt = 0; mt < 4; ++mt)
    #pragma unroll
    for (int nt = 0; nt < 4; ++nt)
      #pragma unroll
      for (int r = 0; r < 4; ++r) {
        int m = m0 + mq + mt * 16 + quad * 4 + r;
        int n = n0 + nq + nt * 16 + l16;
        C[(size_t)m * N + n] = acc[mt][nt][r];
      }
}

// ---------------- conversions / packing ----------------
__global__ __launch_bounds__(256) void cvt_bf(const float* __restrict__ src,
                                              ushort* __restrict__ dst, int n) {
  int i = blockIdx.x * 256 + threadIdx.x;
  if (i < n) dst[i] = f2bf(src[i]);
}

__global__ __launch_bounds__(256) void cvt_sum2_bf(const float* __restrict__ a,
                                                   const float* __restrict__ b,
                                                   ushort* __restrict__ dst, int n) {
  int i = blockIdx.x * 256 + threadIdx.x;
  if (i < n) dst[i] = f2bf(a[i] + b[i]);
}

// pack Wk|Wv|Wgate (+zero pad) into wkvgb[KVGW][2048] bf16
__global__ __launch_bounds__(256) void pack_wkvg(
    const float* __restrict__ Wk, const float* __restrict__ Wv,
    const float* __restrict__ Wg, ushort* __restrict__ dst) {
  int i = blockIdx.x * 256 + threadIdx.x;
  if (i >= KVGW * 2048) return;
  int n = i >> 11, k = i & 2047;
  float v;
  if (n < 128) v = Wk[(size_t)n * 2048 + k];
  else if (n < 256) v = Wv[(size_t)(n - 128) * 2048 + k];
  else if (n < 259) v = Wg[(size_t)(n - 256) * 2048 + k];
  else v = 0.f;
  dst[i] = f2bf(v);
}

// kbf[t][g][d] bf16 from kvg
__global__ __launch_bounds__(256) void cvt_k(const float* __restrict__ kvg,
                                             ushort* __restrict__ kbf) {
  int i = blockIdx.x * 256 + threadIdx.x;  // over T*128
  if (i >= T_SEQ * 128) return;
  int gd = i & 127, t = i >> 7;
  kbf[i] = f2bf(kvg[(size_t)t * KVGW + gd]);
}

// vt[g][d][s] bf16 from kvg v-part
__global__ __launch_bounds__(256) void cvt_vt(const float* __restrict__ kvg,
                                              ushort* __restrict__ vt) {
  int i = blockIdx.x * 256 + threadIdx.x;  // over T*G*D
  if (i >= T_SEQ * NG * HD) return;
  int d = i & 63, g = (i >> 6) & 1, s = i >> 7;
  vt[((size_t)g * HD + d) * T_SEQ + s] =
      f2bf(kvg[(size_t)s * KVGW + 128 + g * 64 + d]);
}

// ---------------- RoPE (in-place on q and kvg's k-part) ----------------
__global__ __launch_bounds__(256) void rope_all(float* __restrict__ q,
                                                float* __restrict__ kvg) {
  const int t = blockIdx.x;
  const float lnb_over = 9.210340371976184f / 32.f;  // ln(10000)/32
  for (int job = threadIdx.x; job < (NHQ + NG) * 32; job += 256) {
    int h = job >> 5, j = job & 31;
    float* base = (h < NHQ) ? (q + ((size_t)t * NHQ + h) * HD)
                            : (kvg + (size_t)t * KVGW + (h - NHQ) * 64);
    float inv = expf(-(float)j * lnb_over);
    float fr = (float)t * inv;
    float c_ = cosf(fr), s_ = sinf(fr);
    float x1 = base[j], x2 = base[j + 32];
    base[j] = x1 * c_ - x2 * s_;
    base[j + 32] = x2 * c_ + x1 * s_;
  }
}

// ---------------- compression: ck/cv[c][g][d] ----------------
__global__ __launch_bounds__(256) void compress_kv(
    const float* __restrict__ kvg,
    const float* __restrict__ Wck, const float* __restrict__ Wcv,
    float* __restrict__ ck, float* __restrict__ cv) {
  const int c = blockIdx.x, g = blockIdx.y;
  const int tid = threadIdx.x;
  const int d = tid & 63, chunk = tid >> 6;
  __shared__ float red[2][4][64];
  float ak = 0.f, av = 0.f;
  for (int f = chunk * 512; f < chunk * 512 + 512; ++f) {
    int i = f >> 6, e = f & 63;
    int trow = c * CSTRIDE + i;
    float kv = kvg[(size_t)trow * KVGW + g * 64 + e];
    float vv = kvg[(size_t)trow * KVGW + 128 + g * 64 + e];
    ak += kv * Wck[((size_t)g * 2048 + f) * HD + d];
    av += vv * Wcv[((size_t)g * 2048 + f) * HD + d];
  }
  red[0][chunk][d] = ak;
  red[1][chunk][d] = av;
  __syncthreads();
  if (tid < 64) {
    ck[((size_t)c * NG + g) * HD + tid] =
        red[0][0][tid] + red[0][1][tid] + red[0][2][tid] + red[0][3][tid];
  } else if (tid < 128) {
    int dd = tid - 64;
    cv[((size_t)c * NG + g) * HD + dd] =
        red[1][0][dd] + red[1][1][dd] + red[1][2][dd] + red[1][3][dd];
  }
}

// ------- compressed attention + block scores + top-16 selection -------
__global__ __launch_bounds__(128) void comp_attn(
    const float* __restrict__ q, const float* __restrict__ ck,
    const float* __restrict__ cv, const float* __restrict__ kvg,
    float* __restrict__ comb, unsigned* __restrict__ sel) {
  const int t = blockIdx.x, g = blockIdx.y;
  const int tid = threadIdx.x;
  __shared__ float qs[16][64];
  __shared__ float p[16][128];
  __shared__ float sc[32];
  for (int i = tid; i < 1024; i += 128)
    qs[i >> 6][i & 63] = q[((size_t)t * NHQ + g * 16 + (i >> 6)) * HD + (i & 63)];
  __syncthreads();
  const int cmaxv = (t >= 31) ? min(126, (t - 31) >> 4) : -1;
  const int nv = cmaxv + 1;
  for (int h = 0; h < 16; ++h) {
    for (int c = tid; c < nv; c += 128) {
      const float* ckp = ck + ((size_t)c * NG + g) * HD;
      float acc = 0.f;
      #pragma unroll
      for (int e = 0; e < 64; ++e) acc += qs[h][e] * ckp[e];
      p[h][c] = acc * SCALE;
    }
  }
  __syncthreads();
  if (tid < 16) {
    const int h = tid;
    float mx = -INFINITY;
    for (int c = 0; c < nv; ++c) mx = fmaxf(mx, p[h][c]);
    float s = 0.f;
    for (int c = 0; c < nv; ++c) { float e_ = expf(p[h][c] - mx); p[h][c] = e_; s += e_; }
    float is = (nv > 0) ? 1.f / s : 0.f;
    for (int c = 0; c < nv; ++c) p[h][c] *= is;
  }
  __syncthreads();
  const float g0 = 1.f / (1.f + expf(-kvg[(size_t)t * KVGW + 256]));
  for (int job = tid; job < 1024; job += 128) {
    int h = job >> 6, d = job & 63;
    float acc = 0.f;
    for (int c = 0; c < nv; ++c) acc += p[h][c] * cv[((size_t)c * NG + g) * HD + d];
    comb[((size_t)t * NHQ + g * 16 + h) * HD + d] = g0 * acc;
  }
  if (tid < 32) {
    const int b = tid, qb = t >> 6;
    float s;
    if (b > qb) s = -INFINITY;
    else if (b == 0 || qb - b < 2) s = INFINITY;
    else {
      s = 0.f;
      int clo = (4 * b - 1 > 0) ? 4 * b - 1 : 0;
      int chi = min(cmaxv, 4 * b + 3);
      for (int c = clo; c <= chi; ++c) {
        float cs_ = 0.f;
        for (int h = 0; h < 16; ++h) cs_ += p[h][c];
        s += cs_;
      }
    }
    sc[b] = s;
  }
  __syncthreads();
  if (tid == 0) {  // top-16, ties -> lowest index (matches jax.lax.top_k)
    unsigned m_ = 0;
    #pragma unroll 1
    for (int it = 0; it < 16; ++it) {
      float best = -INFINITY; int bi = -1;
      for (int b = 0; b < 32; ++b)
        if (sc[b] > best) { best = sc[b]; bi = b; }
      if (bi < 0) break;
      m_ |= 1u << bi;
      sc[bi] = -INFINITY;
    }
    sel[t * NG + g] = m_;
  }
}

// ------- MFMA flash attention, TRANSPOSED layout: S^T = K Q^T so each lane
// owns one query column; softmax reductions are in-lane + 2 swizzles; P^T
// C-regs feed v_mfma_f32_16x16x16_bf16 B-operand directly (k=quad*4+j) for
// O^T = V^T P^T. No LDS for P. Wave = 1 head x 64 queries.
__global__ __launch_bounds__(256, 2) void mfma_attn(
    const ushort* __restrict__ qb16, const ushort* __restrict__ kb16,
    const ushort* __restrict__ vtb, const float* __restrict__ kvg,
    const unsigned* __restrict__ sel, float* __restrict__ comb1,
    float* __restrict__ comb2) {
  const int qb = blockIdx.x, g = blockIdx.y;
  const int hg = blockIdx.z & 3, mode = blockIdx.z >> 2;
  const int tid = threadIdx.x, lane = tid & 63, w = tid >> 6;
  const int quad = lane >> 4, l16 = lane & 15;
  const int head = g * 16 + hg * 4 + w;
  const int t0 = qb * 64;

  __shared__ unsigned sel_s[64];
  if (tid < 64) sel_s[tid] = sel[(size_t)(t0 + tid) * NG + g];
  __syncthreads();

  // Q as B-operand frags: B[n=query l16][k=d]
  short8_t qB[4][2];
  #pragma unroll
  for (int qt = 0; qt < 4; ++qt)
    #pragma unroll
    for (int kd = 0; kd < 2; ++kd)
      qB[qt][kd] = *(const short8_t*)(qb16 +
          ((size_t)(t0 + qt * 16 + l16) * NHQ + head) * HD + kd * 32 + quad * 8);

  unsigned sbq[4];
  #pragma unroll
  for (int qt = 0; qt < 4; ++qt) sbq[qt] = sel_s[qt * 16 + l16];

  float m_[4], l_[4];
  f32x4 acc[4][4];  // O^T tiles [dt][qt]: row=d(quad*4+r), col=query(l16)
  const f32x4 fz = {0.f, 0.f, 0.f, 0.f};
  #pragma unroll
  for (int qt = 0; qt < 4; ++qt) { m_[qt] = -INFINITY; l_[qt] = 0.f; }
  #pragma unroll
  for (int dt = 0; dt < 4; ++dt)
    #pragma unroll
    for (int qt = 0; qt < 4; ++qt) acc[dt][qt] = fz;

  unsigned mrem = 0; int b0 = 0, nb;
  if (mode == 0) {
    unsigned uni = 0;
    for (int i = 0; i < 64; ++i) uni |= sel_s[i];
    mrem = uni; nb = __popc(uni);
  } else {
    b0 = (qb > 8) ? qb - 8 : 0; nb = qb - b0 + 1;
  }

  for (int ib = 0; ib < nb; ++ib) {
    int blk;
    if (mode == 0) { blk = __ffs(mrem) - 1; mrem &= mrem - 1; } else { blk = b0 + ib; }

    // ---- S^T = K Q^T (A = K rows, B = Q rows); 32 MFMAs ----
    f32x4 sp[4][4];  // [kt][qt]: row=key(quad*4+r), col=query(l16)
    #pragma unroll
    for (int kt = 0; kt < 4; ++kt) {
      const ushort* kr = kb16 +
          ((size_t)(blk * 64 + kt * 16 + l16) * NG + g) * HD + quad * 8;
      short8_t kA0 = *(const short8_t*)kr;
      short8_t kA1 = *(const short8_t*)(kr + 32);
      #pragma unroll
      for (int qt = 0; qt < 4; ++qt) {
        f32x4 c = __builtin_amdgcn_mfma_f32_16x16x32_bf16(kA0, qB[qt][0], fz, 0, 0, 0);
        sp[kt][qt] = __builtin_amdgcn_mfma_f32_16x16x32_bf16(kA1, qB[qt][1], c, 0, 0, 0);
      }
    }

    // ---- mask + online softmax: in-lane over 16 keys/tile-col + 2 swizzles ----
    short4_t pB[4][4];  // P^T bf16 [kt][qt] -> direct B-operand for K=16 MFMA
    #pragma unroll
    for (int qt = 0; qt < 4; ++qt) {
      const int qg = t0 + qt * 16 + l16;
      float mx = -INFINITY;
      #pragma unroll
      for (int kt = 0; kt < 4; ++kt)
        #pragma unroll
        for (int r = 0; r < 4; ++r) {
          int key = blk * 64 + kt * 16 + quad * 4 + r;
          bool ok = (key <= qg) &&
                    (mode == 0 ? (((sbq[qt] >> blk) & 1u) != 0) : (qg - key <= 512));
          float s_ = ok ? sp[kt][qt][r] * SCALE : -1e30f;
          sp[kt][qt][r] = s_;
          mx = fmaxf(mx, s_);
        }
      mx = fmaxf(mx, __shfl_xor(mx, 16));
      mx = fmaxf(mx, __shfl_xor(mx, 32));
      float mnew = fmaxf(m_[qt], mx);
      float alpha = __expf(m_[qt] - mnew);
      m_[qt] = mnew;
      float ps = 0.f;
      #pragma unroll
      for (int kt = 0; kt < 4; ++kt) {
        float pv[4];
        #pragma unroll
        for (int r = 0; r < 4; ++r) {
          pv[r] = __expf(sp[kt][qt][r] - mnew);
          ps += pv[r];
        }
        short4_t pb;
        #pragma unroll
        for (int r = 0; r < 4; ++r) pb[r] = (short)f2bf(pv[r]);
        pB[kt][qt] = pb;
      }
      ps += __shfl_xor(ps, 16);
      ps += __shfl_xor(ps, 32);
      l_[qt] = l_[qt] * alpha + ps;
      #pragma unroll
      for (int dt = 0; dt < 4; ++dt) {
        #pragma unroll
        for (int r = 0; r < 4; ++r) acc[dt][qt][r] *= alpha;
      }
    }

    // ---- O^T += V^T P^T : 64 K=16 MFMAs, P straight from registers ----
    #pragma unroll
    for (int kt = 0; kt < 4; ++kt) {
      short4_t vA[4];
      #pragma unroll
      for (int dt = 0; dt < 4; ++dt)
        vA[dt] = *(const short4_t*)(vtb +
            ((size_t)g * HD + dt * 16 + l16) * T_SEQ + blk * 64 + kt * 16 + quad * 4);
      #pragma unroll
      for (int dt = 0; dt < 4; ++dt)
        #pragma unroll
        for (int qt = 0; qt < 4; ++qt)
          acc[dt][qt] = __builtin_amdgcn_mfma_f32_16x16x16bf16_1k(
              vA[dt], pB[kt][qt], acc[dt][qt], 0, 0, 0);
    }
  }

  // ---- epilogue: gate * O^T/l into comb (row=d, col=query) ----
  #pragma unroll
  for (int qt = 0; qt < 4; ++qt) {
    const int t = t0 + qt * 16 + l16;
    const float c_ =
        (1.f / (1.f + __expf(-kvg[(size_t)t * KVGW + 257 + mode]))) / l_[qt];
    #pragma unroll
    for (int dt = 0; dt < 4; ++dt)
      #pragma unroll
      for (int r = 0; r < 4; ++r) {
        const int d = dt * 16 + quad * 4 + r;
        size_t idx = ((size_t)t * NHQ + head) * HD + d;
        if (mode == 0) comb1[idx] += c_ * acc[dt][qt][r];
        else           comb2[idx]  = c_ * acc[dt][qt][r];
      }
  }
}

extern "C" void kernel_launch(void* const* d_in, const int* in_sizes, int n_in,
                              void* d_out, int out_size, void* d_ws, size_t ws_size,
                              hipStream_t stream) {
  const float* x   = (const float*)d_in[0];
  const float* Wq  = (const float*)d_in[1];
  const float* Wk  = (const float*)d_in[2];
  const float* Wv  = (const float*)d_in[3];
  const float* Wo  = (const float*)d_in[4];
  const float* Wg  = (const float*)d_in[5];
  const float* Wck = (const float*)d_in[6];
  const float* Wcv = (const float*)d_in[7];
  float* out = (float*)d_out;
  float* ws = (float*)d_ws;

  // ---- workspace map (float slots) ----
  float* qbuf  = ws;                      // 4,194,304 f  (later comb2 fp32, then wob u16)
  float* comb1 = qbuf + 4194304;          // 4,194,304 f
  float* kvg   = comb1 + 4194304;         //   786,432 f
  float* ckb   = kvg + 786432;            //    16,384 f
  float* cvb   = ckb + 16384;             //    16,384 f
  unsigned* sel = (unsigned*)(cvb + 16384);  //  4,096 u32
  ushort* kbf  = (ushort*)(cvb + 16384 + 4096);  // 262,144 u16 (131,072 f)
  ushort* vtb  = kbf + 262144;            // 262,144 u16
  ushort* wkvgb = vtb + 262144;           // 786,432 u16 (393,216 f)
  ushort* regA = wkvgb + 786432;          // 4,194,304 u16: xb -> combb
  ushort* regB = regA + 4194304;          // 4,194,304 u16: wqb -> qbf
  // total ~56.2 MB
  ushort* xb = regA;      ushort* combb = regA;
  ushort* wqb = regB;     ushort* qbf = regB;
  float* comb2 = qbuf;                    // alias: fp32 q dead after comp_attn
  ushort* wob = (ushort*)qbuf;            // alias: created after cvt_sum2

  const int CV = (4194304 + 255) / 256;
  cvt_bf<<<CV, 256, 0, stream>>>(x, xb, 4194304);
  cvt_bf<<<CV, 256, 0, stream>>>(Wq, wqb, 4194304);
  pack_wkvg<<<(KVGW * 2048 + 255) / 256, 256, 0, stream>>>(Wk, Wv, Wg, wkvgb);

  mgemm<<<dim3(16, 16), 256, 0, stream>>>(xb, wqb, qbuf, 2048, 2048, 2048);
  mgemm<<<dim3(3, 16), 256, 0, stream>>>(xb, wkvgb, kvg, 2048, KVGW, 2048);

  rope_all<<<2048, 256, 0, stream>>>(qbuf, kvg);
  cvt_bf<<<CV, 256, 0, stream>>>(qbuf, qbf, 4194304);  // regB: wqb dead
  cvt_k<<<(262144 + 255) / 256, 256, 0, stream>>>(kvg, kbf);
  cvt_vt<<<(262144 + 255) / 256, 256, 0, stream>>>(kvg, vtb);
  compress_kv<<<dim3(127, 2), 256, 0, stream>>>(kvg, Wck, Wcv, ckb, cvb);
  comp_attn<<<dim3(2048, 2), 128, 0, stream>>>(qbuf, ckb, cvb, kvg, comb1, sel);
  mfma_attn<<<dim3(32, 2, 8), 256, 0, stream>>>(qbf, kbf, vtb, kvg, sel, comb1, comb2);

  cvt_sum2_bf<<<CV, 256, 0, stream>>>(comb1, comb2, combb, 4194304);  // regA: xb dead
  cvt_bf<<<CV, 256, 0, stream>>>(Wo, wob, 4194304);                   // qbuf region dead
  mgemm<<<dim3(16, 16), 256, 0, stream>>>(combb, wob, out, 2048, 2048, 2048);
}